// Round 13
// baseline (177.327 us; speedup 1.0000x reference)
//
#include <hip/hip_runtime.h>

typedef unsigned short u16;
typedef __bf16 bf16;
typedef bf16 bf16x8 __attribute__((ext_vector_type(8)));
typedef float f32x4 __attribute__((ext_vector_type(4)));
typedef float f32x16 __attribute__((ext_vector_type(16)));

#define SEQ     2048
#define BATCH   2
#define DM      1024
#define DI      1024
#define NROW    (BATCH*SEQ)      // 4096
#define NSTATE  16
#define NCHUNK  64
#define CLEN    32               // SEQ / NCHUNK

static_assert(SEQ == NCHUNK * CLEN, "chunking must cover SEQ");

__device__ __forceinline__ u16 f2bf(float f) {
  unsigned u = __builtin_bit_cast(unsigned, f);
  u += 0x7FFFu + ((u >> 16) & 1u);   // round-to-nearest-even
  return (u16)(u >> 16);
}
__device__ __forceinline__ float bf2f(u16 u) {
  return __builtin_bit_cast(float, (unsigned)u << 16);
}
__device__ __forceinline__ float sigm(float x) { return 1.f / (1.f + __expf(-x)); }

__device__ __forceinline__ void gload16(const u16* g, u16* l) {
  __builtin_amdgcn_global_load_lds((const __attribute__((address_space(1))) void*)g,
                                   (__attribute__((address_space(3))) void*)l,
                                   16, 0, 0);
}

// ---------------- fused fp32 -> bf16 convert for all 4 tensors ----------------
__global__ __launch_bounds__(256) void k_cvt_all(
    const float* __restrict__ x, const float* __restrict__ Win,
    const float* __restrict__ Wdt, const float* __restrict__ Wout,
    u16* __restrict__ xbf, u16* __restrict__ winbf,
    u16* __restrict__ wdtbf, u16* __restrict__ woutbf)
{
  long i = (long)blockIdx.x * 256 + threadIdx.x;
  const float* src; u16* dst; long off;
  if (i < 1048576)            { src = x;    dst = xbf;    off = i; }
  else if (i < 1572864)       { src = Win;  dst = winbf;  off = i - 1048576; }
  else if (i < 1835008)       { src = Wdt;  dst = wdtbf;  off = i - 1572864; }
  else                        { src = Wout; dst = woutbf; off = i - 1835008; }
  float4 v = reinterpret_cast<const float4*>(src)[off];
  ushort4 o;
  o.x = f2bf(v.x); o.y = f2bf(v.y); o.z = f2bf(v.z); o.w = f2bf(v.w);
  reinterpret_cast<ushort4*>(dst)[off] = o;
}

// ---------------- GEMM1 (R12-proven): 128x128, BK=64, 32x32x16 frags ----------
// EPI1: bf16 x_proj (cols<DI) / bf16 silu(res) (cols>=DI)
__global__ __launch_bounds__(256, 2) void k_gemm1(
    const u16* __restrict__ A, const u16* __restrict__ B,
    u16* __restrict__ outb, u16* __restrict__ outb2, int M, int N, int K)
{
  __shared__ __align__(16) u16 sA[2 * 128 * 64];
  __shared__ __align__(16) u16 sB[2 * 128 * 64];
  const int t = threadIdx.x;
  const int wave = t >> 6, lane = t & 63;
  const int la = lane & 31, hi = lane >> 5;
  const int wr = wave >> 1, wc = wave & 1;

  const int nwg = gridDim.x, bid = blockIdx.x;
  const int wg  = (bid & 7) * (nwg >> 3) + (bid >> 3);
  const long bm = (long)(wg / 16) * 128;
  const long bn = (long)(wg % 16) * 128;

  f32x16 acc[2][2] = {};

  const int srow = t >> 3;                               // 0..31
  const int gslot8 = (((t & 7) ^ (srow & 7)) * 8);       // pre-swizzled source
  const u16* gA0 = A + (bm + srow) * (long)K + gslot8;
  const u16* gB0 = B + (bn + srow) * (long)K + gslot8;

  auto STAGE = [&](int buf, int k0) {
    #pragma unroll
    for (int i = 0; i < 4; ++i)
      gload16(gA0 + (long)i * 32 * K + k0, &sA[buf * 8192 + i * 2048 + wave * 512]);
    #pragma unroll
    for (int i = 0; i < 4; ++i)
      gload16(gB0 + (long)i * 32 * K + k0, &sB[buf * 8192 + i * 2048 + wave * 512]);
  };

  const int xr = la & 7;
  STAGE(0, 0);
  __syncthreads();
  int cur = 0;
  for (int k0 = 0; k0 < K; k0 += 64) {
    if (k0 + 64 < K) STAGE(cur ^ 1, k0 + 64);
    const u16* pa = &sA[cur * 8192];
    const u16* pb = &sB[cur * 8192];
    bf16x8 af[4][2], bfr[4][2];
    #pragma unroll
    for (int ks = 0; ks < 4; ++ks) {
      const int co = ((ks * 2 + hi) ^ xr) * 8;
      #pragma unroll
      for (int mi = 0; mi < 2; ++mi)
        af[ks][mi] = *reinterpret_cast<const bf16x8*>(pa + (wr * 64 + mi * 32 + la) * 64 + co);
      #pragma unroll
      for (int ni = 0; ni < 2; ++ni)
        bfr[ks][ni] = *reinterpret_cast<const bf16x8*>(pb + (wc * 64 + ni * 32 + la) * 64 + co);
    }
    #pragma unroll
    for (int ks = 0; ks < 4; ++ks)
      #pragma unroll
      for (int mi = 0; mi < 2; ++mi)
        #pragma unroll
        for (int ni = 0; ni < 2; ++ni)
          acc[mi][ni] = __builtin_amdgcn_mfma_f32_32x32x16_bf16(
              af[ks][mi], bfr[ks][ni], acc[mi][ni], 0, 0, 0);
    __syncthreads();
    cur ^= 1;
  }

  #pragma unroll
  for (int mi = 0; mi < 2; ++mi) {
    const long rowb = bm + wr * 64 + mi * 32 + 4 * hi;
    #pragma unroll
    for (int ni = 0; ni < 2; ++ni) {
      const long col = bn + wc * 64 + ni * 32 + la;
      #pragma unroll
      for (int q = 0; q < 4; ++q)
        #pragma unroll
        for (int j = 0; j < 4; ++j) {
          const float v = acc[mi][ni][q * 4 + j];
          const long r = rowb + q * 8 + j;
          if (bn < DI) outb[r * DI + col] = f2bf(v);                    // x_proj
          else         outb2[r * DI + (col - DI)] = f2bf(v * sigm(v));  // silu(res)
        }
    }
  }
}

// ---------------- split-K GEMM (m97 geometry): 128x128, BK=32, 16x16x32 ------
// grid = 32(M) x 8(N) x 2(K-slices) = 512 blocks (2/CU). fp32 partial store.
__global__ __launch_bounds__(256, 2) void k_gemm_sk(
    const u16* __restrict__ A, const u16* __restrict__ B,
    float* __restrict__ part, int M, int N, int K)
{
  __shared__ __align__(16) u16 sA[2 * 128 * 32];
  __shared__ __align__(16) u16 sB[2 * 128 * 32];
  const int t = threadIdx.x;
  const int wave = t >> 6, lane = t & 63;
  const int lr = lane & 15, kb = lane >> 4;
  const int wr = wave >> 1, wc = wave & 1;

  const int nwg = gridDim.x, bid = blockIdx.x;
  const int wg  = (bid & 7) * (nwg >> 3) + (bid >> 3);
  const int ks  = wg >> 8;               // 0..1
  const int rem = wg & 255;
  const long bm = (long)(rem >> 3) * 128;
  const long bn = (long)(rem & 7) * 128;
  const int kbase = ks * (K / 2);

  f32x4 acc[4][4] = {};

  // staging: 64 rows x 32 cols per call; thread t -> row t>>2, granule t&3,
  // global granule (t&3)^(row&3) (pre-swizzled source for linear LDS dest).
  const int srow = t >> 2;                            // 0..63
  const int gslot8 = (((t & 3) ^ (srow & 3)) * 8);
  const u16* gA0 = A + (bm + srow) * (long)K + gslot8 + kbase;
  const u16* gB0 = B + (bn + srow) * (long)K + gslot8 + kbase;

  auto STAGE = [&](int buf, int k0) {
    gload16(gA0 + k0,                &sA[buf * 4096 + wave * 512]);
    gload16(gA0 + 64 * (long)K + k0, &sA[buf * 4096 + 2048 + wave * 512]);
    gload16(gB0 + k0,                &sB[buf * 4096 + wave * 512]);
    gload16(gB0 + 64 * (long)K + k0, &sB[buf * 4096 + 2048 + wave * 512]);
  };

  const int xr = lr & 3;
  const int co = ((kb ^ xr) * 8);
  STAGE(0, 0);
  __syncthreads();
  int cur = 0;
  const int KS = K / 2;
  for (int k0 = 0; k0 < KS; k0 += 32) {
    if (k0 + 32 < KS) STAGE(cur ^ 1, k0 + 32);
    const u16* pa = &sA[cur * 4096];
    const u16* pb = &sB[cur * 4096];
    bf16x8 af[4], bfr[4];
    #pragma unroll
    for (int mi = 0; mi < 4; ++mi)
      af[mi] = *reinterpret_cast<const bf16x8*>(pa + (wr * 64 + mi * 16 + lr) * 32 + co);
    #pragma unroll
    for (int ni = 0; ni < 4; ++ni)
      bfr[ni] = *reinterpret_cast<const bf16x8*>(pb + (wc * 64 + ni * 16 + lr) * 32 + co);
    #pragma unroll
    for (int mi = 0; mi < 4; ++mi)
      #pragma unroll
      for (int ni = 0; ni < 4; ++ni)
        acc[mi][ni] = __builtin_amdgcn_mfma_f32_16x16x32_bf16(
            af[mi], bfr[ni], acc[mi][ni], 0, 0, 0);
    __syncthreads();
    cur ^= 1;
  }

  float* po = part + (long)ks * M * N;
  #pragma unroll
  for (int mi = 0; mi < 4; ++mi) {
    const long row0 = bm + wr * 64 + mi * 16 + kb * 4;
    #pragma unroll
    for (int ni = 0; ni < 4; ++ni) {
      const long col = bn + wc * 64 + ni * 16 + lr;
      #pragma unroll
      for (int j = 0; j < 4; ++j)
        po[(row0 + j) * N + col] = acc[mi][ni][j];
    }
  }
}

// ---------------- reduce G2: p0+p1+bias -> softplus -> delta + fused scanA ----
// block = (chunk c 0..127, d-block 0..7); 32 rows x 128 cols
__global__ __launch_bounds__(256) void k_redG2(
    const float* __restrict__ part, const float* __restrict__ bias,
    const u16* __restrict__ xc, const float* __restrict__ A_log,
    const float* __restrict__ Bp, u16* __restrict__ delta_bf,
    float* __restrict__ hfin, float* __restrict__ sumdt)
{
  __shared__ float sD[32 * 128];
  const int t = threadIdx.x;
  const int c  = blockIdx.x >> 3;        // global chunk 0..127
  const int db = blockIdx.x & 7;
  const int r0 = c * 32;
  const int d0 = db * 128;
  const float* p0 = part;
  const float* p1 = part + (long)NROW * DI;

  #pragma unroll
  for (int v = 0; v < 4; ++v) {
    const int e = t + v * 256;           // 0..1023 float4s
    const int row = e >> 5, cf = (e & 31) * 4;
    const long gi = (long)(r0 + row) * DI + d0 + cf;
    float4 a = *reinterpret_cast<const float4*>(&p0[gi]);
    float4 b = *reinterpret_cast<const float4*>(&p1[gi]);
    float z0 = a.x + b.x + bias[d0 + cf + 0];
    float z1 = a.y + b.y + bias[d0 + cf + 1];
    float z2 = a.z + b.z + bias[d0 + cf + 2];
    float z3 = a.w + b.w + bias[d0 + cf + 3];
    float s0 = fmaxf(z0, 0.f) + log1pf(__expf(-fabsf(z0)));
    float s1 = fmaxf(z1, 0.f) + log1pf(__expf(-fabsf(z1)));
    float s2 = fmaxf(z2, 0.f) + log1pf(__expf(-fabsf(z2)));
    float s3 = fmaxf(z3, 0.f) + log1pf(__expf(-fabsf(z3)));
    ushort4 o = {f2bf(s0), f2bf(s1), f2bf(s2), f2bf(s3)};
    *reinterpret_cast<ushort4*>(&delta_bf[gi]) = o;
    sD[row * 128 + cf] = s0; sD[row * 128 + cf + 1] = s1;
    sD[row * 128 + cf + 2] = s2; sD[row * 128 + cf + 3] = s3;
  }
  __syncthreads();

  // scanA: 128 d x 2 n-halves
  const int dl = t & 127, half = t >> 7;
  const int d = d0 + dl;
  const int b = c >> 6, cb = c & 63;
  float Aa[8], Bb[8], h[8];
  #pragma unroll
  for (int n = 0; n < 8; ++n) {
    Aa[n] = -__expf(A_log[d * NSTATE + half * 8 + n]);
    Bb[n] = Bp[d * NSTATE + half * 8 + n];
    h[n] = 0.f;
  }
  float sdt = 0.f;
  for (int i = 0; i < CLEN; ++i) {
    float dt = sD[i * 128 + dl];
    float xv = bf2f(xc[(long)(r0 + i) * DI + d]);
    sdt += dt;
    float dx = dt * xv;
    #pragma unroll
    for (int n = 0; n < 8; ++n) {
      float da = __expf(dt * Aa[n]);
      h[n] = fmaf(da, h[n], dx * Bb[n]);
    }
  }
  const long hb = ((long)(b * NCHUNK + cb) * NSTATE + half * 8) * DI + d;
  #pragma unroll
  for (int n = 0; n < 8; ++n) hfin[hb + (long)n * DI] = h[n];
  if (half == 0) sumdt[(long)(b * NCHUNK + cb) * DI + d] = sdt;
}

// ---------------- reduce G3: out = p0 + p1 (fp32) ----------------
__global__ __launch_bounds__(256) void k_redG3(
    const float* __restrict__ part, float* __restrict__ out)
{
  const long i = (long)blockIdx.x * 256 + threadIdx.x;   // float4 index
  const float4 a = reinterpret_cast<const float4*>(part)[i];
  const float4 b = reinterpret_cast<const float4*>(part + (long)NROW * DM)[i];
  float4 o = {a.x + b.x, a.y + b.y, a.z + b.z, a.w + b.w};
  reinterpret_cast<float4*>(out)[i] = o;
}

// ---------------- causal depthwise conv (K=4) + silu -> bf16, x8 vectorized ----
__global__ __launch_bounds__(256) void k_conv(
    const u16* __restrict__ xproj, const float* __restrict__ convw,
    const float* __restrict__ convb, u16* __restrict__ xcbf)
{
  const int idx = blockIdx.x * 256 + threadIdx.x;   // (m, d-octet)
  const int d0 = (idx & 127) * 8;
  const int m  = idx >> 7;
  const int l  = m & (SEQ - 1);
  float acc[8];
  #pragma unroll
  for (int di = 0; di < 8; ++di) acc[di] = convb[d0 + di];
  #pragma unroll
  for (int k = 0; k < 4; ++k) {
    if (l + k - 3 >= 0) {
      ushort4 v2 = *reinterpret_cast<const ushort4*>(&xproj[(long)(m + k - 3) * DI + d0]);
      ushort4 v3 = *reinterpret_cast<const ushort4*>(&xproj[(long)(m + k - 3) * DI + d0 + 4]);
      const u16 vv[8] = {v2.x, v2.y, v2.z, v2.w, v3.x, v3.y, v3.z, v3.w};
      #pragma unroll
      for (int di = 0; di < 8; ++di)
        acc[di] = fmaf(convw[(d0 + di) * 4 + k], bf2f(vv[di]), acc[di]);
    }
  }
  u16 ov[8];
  #pragma unroll
  for (int di = 0; di < 8; ++di) {
    float s = acc[di] * sigm(acc[di]);
    ov[di] = f2bf(s);
  }
  ushort4 o0 = {ov[0], ov[1], ov[2], ov[3]}, o1 = {ov[4], ov[5], ov[6], ov[7]};
  *reinterpret_cast<ushort4*>(&xcbf[(long)m * DI + d0]) = o0;
  *reinterpret_cast<ushort4*>(&xcbf[(long)m * DI + d0 + 4]) = o1;
}

// ---------------- scan combine + pass B ----------------
__global__ __launch_bounds__(256) void k_combine(
    const float* __restrict__ hfin, const float* __restrict__ sumdt_buf,
    const float* __restrict__ A_log, float* __restrict__ hstart)
{
  const int idx = blockIdx.x * 256 + threadIdx.x;   // 32768 threads
  const int d = idx & (DI - 1);
  const int n = (idx >> 10) & (NSTATE - 1);
  const int b = idx >> 14;
  const float Aa = -__expf(A_log[d * NSTATE + n]);
  float h = 0.f;
  for (int c = 0; c < NCHUNK; ++c) {
    const long sb = ((long)(b * NCHUNK + c) * NSTATE + n) * DI + d;
    hstart[sb] = h;
    float sdt = sumdt_buf[(long)(b * NCHUNK + c) * DI + d];
    h = fmaf(__expf(Aa * sdt), h, hfin[sb]);
  }
}

__global__ __launch_bounds__(256) void k_scanB(
    const u16* __restrict__ delta, const u16* __restrict__ xc,
    const float* __restrict__ A_log, const float* __restrict__ Bp,
    const float* __restrict__ Cp, const float* __restrict__ Dp,
    const u16* __restrict__ sres, const float* __restrict__ hstart,
    u16* __restrict__ gated)
{
  const int tid = threadIdx.x, blk = blockIdx.x;    // 512 blocks
  const int d = (blk & 3) * 256 + tid;
  const int c = (blk >> 2) & (NCHUNK - 1);
  const int b = blk >> 8;
  float Aa[NSTATE], Bb[NSTATE], Cc[NSTATE], h[NSTATE];
  #pragma unroll
  for (int n = 0; n < NSTATE; ++n) {
    Aa[n] = -__expf(A_log[d * NSTATE + n]);
    Bb[n] = Bp[d * NSTATE + n];
    Cc[n] = Cp[d * NSTATE + n];
  }
  const float Dd = Dp[d];
  const long sb = ((long)(b * NCHUNK + c) * NSTATE) * DI + d;
  #pragma unroll
  for (int n = 0; n < NSTATE; ++n) h[n] = hstart[sb + (long)n * DI];
  const long base = ((long)(b * SEQ + c * CLEN)) * DI + d;
  for (int i = 0; i < CLEN; ++i) {
    float dt = bf2f(delta[base + (long)i * DI]);
    float x  = bf2f(xc[base + (long)i * DI]);
    float dx = dt * x;
    float y = 0.f;
    #pragma unroll
    for (int n = 0; n < NSTATE; ++n) {
      float da = __expf(dt * Aa[n]);
      h[n] = fmaf(da, h[n], dx * Bb[n]);
      y = fmaf(h[n], Cc[n], y);
    }
    float xs = fmaf(x, Dd, y);
    float g = xs * bf2f(sres[base + (long)i * DI]);
    gated[base + (long)i * DI] = f2bf(g);
  }
}

// ---------------- host launch ----------------
extern "C" void kernel_launch(void* const* d_in, const int* in_sizes, int n_in,
                              void* d_out, int out_size, void* d_ws, size_t ws_size,
                              hipStream_t stream)
{
  const float* x      = (const float*)d_in[0];
  const float* W_in   = (const float*)d_in[1];
  const float* conv_w = (const float*)d_in[2];
  const float* conv_b = (const float*)d_in[3];
  const float* W_dt   = (const float*)d_in[4];
  const float* b_dt   = (const float*)d_in[5];
  const float* A_log  = (const float*)d_in[6];
  const float* Bp     = (const float*)d_in[7];
  const float* Cp     = (const float*)d_in[8];
  const float* Dp     = (const float*)d_in[9];
  const float* W_out  = (const float*)d_in[10];
  float* out = (float*)d_out;

  const long MD = (long)NROW * DI;          // 4194304

  char* ws = (char*)d_ws;
  u16*   xproj_bf = (u16*)ws;               ws += MD * 2;   // x_proj bf16
  u16*   silu_bf  = (u16*)ws;               ws += MD * 2;   // silu(res) bf16
  u16*   delta_bf = (u16*)ws;               ws += MD * 2;   // softplus out bf16
  u16*   xc_bf    = (u16*)ws;               ws += MD * 2;   // conv+silu bf16
  u16*   xbf      = (u16*)ws;               ws += MD * 2;   // x bf16; later gated
  u16*   Win_bf   = (u16*)ws;               ws += (long)2 * DI * DM * 2;
  u16*   Wdt_bf   = (u16*)ws;               ws += (long)DI * DI * 2;
  u16*   Wout_bf  = (u16*)ws;               ws += (long)DM * DI * 2;
  float* hfin     = (float*)ws;             ws += (long)BATCH * NCHUNK * NSTATE * DI * 4;
  float* sumdt    = (float*)ws;             ws += (long)BATCH * NCHUNK * DI * 4;
  float* hstart   = (float*)ws;             ws += (long)BATCH * NCHUNK * NSTATE * DI * 4;
  float* part     = (float*)ws;             ws += MD * 2 * 4;   // 2 fp32 partials

  u16* gated = xbf;      // alias: x_bf16 dead before gated is written

  // 1) fused fp32 -> bf16 conversion (x, W_in, W_dt, W_out)
  k_cvt_all<<<dim3(8192), dim3(256), 0, stream>>>(
      x, W_in, W_dt, W_out, xbf, Win_bf, Wdt_bf, Wout_bf);

  // 2) GEMM1: xr = x @ W_in^T -> x_proj (bf16), silu_res (bf16); grid 512
  k_gemm1<<<dim3(512), dim3(256), 0, stream>>>(
      xbf, Win_bf, xproj_bf, silu_bf, NROW, 2 * DI, DM);

  // 3) causal depthwise conv + silu -> bf16 (x8 vectorized)
  k_conv<<<dim3((unsigned)(MD / 8 / 256)), dim3(256), 0, stream>>>(
      xproj_bf, conv_w, conv_b, xc_bf);

  // 4) GEMM2 split-K=2 -> fp32 partials; reduce fuses softplus + scanA
  k_gemm_sk<<<dim3(512), dim3(256), 0, stream>>>(
      xc_bf, Wdt_bf, part, NROW, DI, DI);
  k_redG2<<<dim3(1024), dim3(256), 0, stream>>>(
      part, b_dt, xc_bf, A_log, Bp, delta_bf, hfin, sumdt);

  // 5) combine + scanB
  k_combine<<<dim3(BATCH * NSTATE * DI / 256), dim3(256), 0, stream>>>(
      hfin, sumdt, A_log, hstart);
  k_scanB<<<dim3(BATCH * NCHUNK * (DI / 256)), dim3(256), 0, stream>>>(
      delta_bf, xc_bf, A_log, Bp, Cp, Dp, silu_bf, hstart, gated);

  // 6) GEMM3 split-K=2 -> fp32 partials; reduce -> out (fp32)
  k_gemm_sk<<<dim3(512), dim3(256), 0, stream>>>(
      gated, Wout_bf, part, NROW, DM, DI);
  k_redG3<<<dim3((unsigned)(MD / 4 / 256)), dim3(256), 0, stream>>>(part, out);
}

// Round 14
// 177.152 us; speedup vs baseline: 1.0010x; 1.0010x over previous
//
#include <hip/hip_runtime.h>

typedef unsigned short u16;
typedef __bf16 bf16;
typedef bf16 bf16x8 __attribute__((ext_vector_type(8)));
typedef float f32x4 __attribute__((ext_vector_type(4)));
typedef float f32x16 __attribute__((ext_vector_type(16)));

#define SEQ     2048
#define BATCH   2
#define DM      1024
#define DI      1024
#define NROW    (BATCH*SEQ)      // 4096
#define NSTATE  16
#define NCHUNK  64
#define CLEN    32               // SEQ / NCHUNK

static_assert(SEQ == NCHUNK * CLEN, "chunking must cover SEQ");

__device__ __forceinline__ u16 f2bf(float f) {
  unsigned u = __builtin_bit_cast(unsigned, f);
  u += 0x7FFFu + ((u >> 16) & 1u);   // round-to-nearest-even
  return (u16)(u >> 16);
}
__device__ __forceinline__ float bf2f(u16 u) {
  return __builtin_bit_cast(float, (unsigned)u << 16);
}
__device__ __forceinline__ float sigm(float x) { return 1.f / (1.f + __expf(-x)); }

__device__ __forceinline__ void gload16(const u16* g, u16* l) {
  __builtin_amdgcn_global_load_lds((const __attribute__((address_space(1))) void*)g,
                                   (__attribute__((address_space(3))) void*)l,
                                   16, 0, 0);
}

// ---------------- fused fp32 -> bf16 convert for all 4 tensors ----------------
__global__ __launch_bounds__(256) void k_cvt_all(
    const float* __restrict__ x, const float* __restrict__ Win,
    const float* __restrict__ Wdt, const float* __restrict__ Wout,
    u16* __restrict__ xbf, u16* __restrict__ winbf,
    u16* __restrict__ wdtbf, u16* __restrict__ woutbf)
{
  long i = (long)blockIdx.x * 256 + threadIdx.x;
  const float* src; u16* dst; long off;
  if (i < 1048576)            { src = x;    dst = xbf;    off = i; }
  else if (i < 1572864)       { src = Win;  dst = winbf;  off = i - 1048576; }
  else if (i < 1835008)       { src = Wdt;  dst = wdtbf;  off = i - 1572864; }
  else                        { src = Wout; dst = woutbf; off = i - 1835008; }
  float4 v = reinterpret_cast<const float4*>(src)[off];
  ushort4 o;
  o.x = f2bf(v.x); o.y = f2bf(v.y); o.z = f2bf(v.z); o.w = f2bf(v.w);
  reinterpret_cast<ushort4*>(dst)[off] = o;
}

// ---------------- GEMM1 (R12-proven): 128x128, BK=64, 32x32x16 frags ----------
// EPI1: bf16 x_proj (cols<DI) / bf16 silu(res) (cols>=DI)
__global__ __launch_bounds__(256, 2) void k_gemm1(
    const u16* __restrict__ A, const u16* __restrict__ B,
    u16* __restrict__ outb, u16* __restrict__ outb2, int M, int N, int K)
{
  __shared__ __align__(16) u16 sA[2 * 128 * 64];
  __shared__ __align__(16) u16 sB[2 * 128 * 64];
  const int t = threadIdx.x;
  const int wave = t >> 6, lane = t & 63;
  const int la = lane & 31, hi = lane >> 5;
  const int wr = wave >> 1, wc = wave & 1;

  const int nwg = gridDim.x, bid = blockIdx.x;
  const int wg  = (bid & 7) * (nwg >> 3) + (bid >> 3);
  const long bm = (long)(wg / 16) * 128;
  const long bn = (long)(wg % 16) * 128;

  f32x16 acc[2][2] = {};

  const int srow = t >> 3;                               // 0..31
  const int gslot8 = (((t & 7) ^ (srow & 7)) * 8);       // pre-swizzled source
  const u16* gA0 = A + (bm + srow) * (long)K + gslot8;
  const u16* gB0 = B + (bn + srow) * (long)K + gslot8;

  auto STAGE = [&](int buf, int k0) {
    #pragma unroll
    for (int i = 0; i < 4; ++i)
      gload16(gA0 + (long)i * 32 * K + k0, &sA[buf * 8192 + i * 2048 + wave * 512]);
    #pragma unroll
    for (int i = 0; i < 4; ++i)
      gload16(gB0 + (long)i * 32 * K + k0, &sB[buf * 8192 + i * 2048 + wave * 512]);
  };

  const int xr = la & 7;
  STAGE(0, 0);
  __syncthreads();
  int cur = 0;
  for (int k0 = 0; k0 < K; k0 += 64) {
    if (k0 + 64 < K) STAGE(cur ^ 1, k0 + 64);
    const u16* pa = &sA[cur * 8192];
    const u16* pb = &sB[cur * 8192];
    bf16x8 af[4][2], bfr[4][2];
    #pragma unroll
    for (int ks = 0; ks < 4; ++ks) {
      const int co = ((ks * 2 + hi) ^ xr) * 8;
      #pragma unroll
      for (int mi = 0; mi < 2; ++mi)
        af[ks][mi] = *reinterpret_cast<const bf16x8*>(pa + (wr * 64 + mi * 32 + la) * 64 + co);
      #pragma unroll
      for (int ni = 0; ni < 2; ++ni)
        bfr[ks][ni] = *reinterpret_cast<const bf16x8*>(pb + (wc * 64 + ni * 32 + la) * 64 + co);
    }
    #pragma unroll
    for (int ks = 0; ks < 4; ++ks)
      #pragma unroll
      for (int mi = 0; mi < 2; ++mi)
        #pragma unroll
        for (int ni = 0; ni < 2; ++ni)
          acc[mi][ni] = __builtin_amdgcn_mfma_f32_32x32x16_bf16(
              af[ks][mi], bfr[ks][ni], acc[mi][ni], 0, 0, 0);
    __syncthreads();
    cur ^= 1;
  }

  #pragma unroll
  for (int mi = 0; mi < 2; ++mi) {
    const long rowb = bm + wr * 64 + mi * 32 + 4 * hi;
    #pragma unroll
    for (int ni = 0; ni < 2; ++ni) {
      const long col = bn + wc * 64 + ni * 32 + la;
      #pragma unroll
      for (int q = 0; q < 4; ++q)
        #pragma unroll
        for (int j = 0; j < 4; ++j) {
          const float v = acc[mi][ni][q * 4 + j];
          const long r = rowb + q * 8 + j;
          if (bn < DI) outb[r * DI + col] = f2bf(v);                    // x_proj
          else         outb2[r * DI + (col - DI)] = f2bf(v * sigm(v));  // silu(res)
        }
    }
  }
}

// ---------------- split-K-IN-BLOCK GEMM: 128x128 tile, 512 threads -----------
// waves 0-3: K[0,K/2); waves 4-7: K[K/2,K). Each group has its own 2-buffer
// LDS staging (32 KB in flight per block per iteration = 2 "virtual blocks").
// Group-1 acc -> LDS exchange; group-0 adds (exact, deterministic) + epilogue.
// EPI 0: fp32 out. EPI 3: bf16 softplus(delta) + fused scanA.
template<int EPI>
__global__ __launch_bounds__(512, 1) void k_gemm_skb(
    const u16* __restrict__ A, const u16* __restrict__ B,
    float* __restrict__ outf, u16* __restrict__ outb,
    const float* __restrict__ bias,
    const float* __restrict__ A_log, const float* __restrict__ Bp,
    float* __restrict__ hfin, float* __restrict__ sumdt,
    int M, int N, int K)
{
  __shared__ __align__(16) u16 sStage[32768];   // 64 KB: [g][buf][A 8KB | B 8KB]
  __shared__ __align__(16) float sX[16384];     // 64 KB: exchange, then sDelta
  const int t = threadIdx.x;
  const int g  = t >> 8;            // k-group 0/1
  const int tg = t & 255;
  const int wl = (t >> 6) & 3;      // wave within group
  const int lane = t & 63;
  const int lr = lane & 15, kb = lane >> 4;
  const int wr = wl >> 1, wc = wl & 1;

  const int bid = blockIdx.x;                    // 256 blocks
  const int wg  = (bid & 7) * 32 + (bid >> 3);   // XCD swizzle (256 % 8 == 0)
  const long bm = (long)(wg >> 3) * 128;
  const long bn = (long)(wg & 7) * 128;
  const int kbase = g * (K / 2);

  f32x4 acc[4][4] = {};

  // staging per group: 64 rows x 32 cols per gload-pair; thread tg -> row tg>>2,
  // LDS granule tg&3, global granule (tg&3)^(row&3) (pre-swizzled source).
  const int srow = tg >> 2;                           // 0..63
  const int gslot8 = (((tg & 3) ^ (srow & 3)) * 8);
  const u16* gA0 = A + (bm + srow) * (long)K + gslot8 + kbase;
  const u16* gB0 = B + (bn + srow) * (long)K + gslot8 + kbase;
  u16* lbase = &sStage[g * 16384];
  const int wig = wl * 512;

  auto STAGE = [&](int buf, int k0) {
    gload16(gA0 + k0,                 lbase + buf * 8192 + wig);
    gload16(gA0 + 64 * (long)K + k0,  lbase + buf * 8192 + 2048 + wig);
    gload16(gB0 + k0,                 lbase + buf * 8192 + 4096 + wig);
    gload16(gB0 + 64 * (long)K + k0,  lbase + buf * 8192 + 6144 + wig);
  };

  const int co = ((kb ^ (lr & 3)) * 8);
  STAGE(0, 0);
  __syncthreads();
  int cur = 0;
  const int KS = K / 2;
  for (int k0 = 0; k0 < KS; k0 += 32) {
    if (k0 + 32 < KS) STAGE(cur ^ 1, k0 + 32);
    const u16* pa = lbase + cur * 8192;
    const u16* pb = pa + 4096;
    bf16x8 af[4], bfr[4];
    #pragma unroll
    for (int mi = 0; mi < 4; ++mi)
      af[mi] = *reinterpret_cast<const bf16x8*>(pa + (wr * 64 + mi * 16 + lr) * 32 + co);
    #pragma unroll
    for (int ni = 0; ni < 4; ++ni)
      bfr[ni] = *reinterpret_cast<const bf16x8*>(pb + (wc * 64 + ni * 16 + lr) * 32 + co);
    #pragma unroll
    for (int mi = 0; mi < 4; ++mi)
      #pragma unroll
      for (int ni = 0; ni < 4; ++ni)
        acc[mi][ni] = __builtin_amdgcn_mfma_f32_16x16x32_bf16(
            af[mi], bfr[ni], acc[mi][ni], 0, 0, 0);
    __syncthreads();
    cur ^= 1;
  }

  // ---- K-halves reduce through LDS (exact: one fp32 add, fixed order) ----
  if (g == 1) {
    #pragma unroll
    for (int mi = 0; mi < 4; ++mi)
      #pragma unroll
      for (int ni = 0; ni < 4; ++ni)
        #pragma unroll
        for (int j = 0; j < 4; ++j)
          sX[(mi * 16 + ni * 4 + j) * 256 + tg] = acc[mi][ni][j];
  }
  __syncthreads();
  if (g == 0) {
    #pragma unroll
    for (int mi = 0; mi < 4; ++mi)
      #pragma unroll
      for (int ni = 0; ni < 4; ++ni)
        #pragma unroll
        for (int j = 0; j < 4; ++j)
          acc[mi][ni][j] += sX[(mi * 16 + ni * 4 + j) * 256 + tg];
  }
  if (EPI == 3) __syncthreads();   // exchange reads done before sX reuse as sDelta

  if (g == 0) {
    #pragma unroll
    for (int mi = 0; mi < 4; ++mi) {
      const long row0 = bm + wr * 64 + mi * 16 + kb * 4;   // C/D row=(lane>>4)*4+j
      #pragma unroll
      for (int ni = 0; ni < 4; ++ni) {
        const long col = bn + wc * 64 + ni * 16 + lr;      // C/D col=lane&15
        #pragma unroll
        for (int j = 0; j < 4; ++j) {
          const float v = acc[mi][ni][j];
          const long r = row0 + j;
          if (EPI == 0) {
            outf[r * N + col] = v;
          } else {
            float z = v + bias[col];
            float sp = fmaxf(z, 0.f) + log1pf(__expf(-fabsf(z)));
            outb[r * N + col] = f2bf(sp);                  // delta bf16 for scanB
            sX[(int)(r - bm) * 128 + (int)(col - bn)] = sp;
          }
        }
      }
    }
  }

  if (EPI == 3) {
    // fused scanA: 4 chunks x 128 d = 512 tasks, one per thread
    __syncthreads();
    const int dl = t & 127;
    const int cl = t >> 7;               // 0..3
    const int d  = (int)bn + dl;
    const int b  = (int)(bm >> 11);
    const int cg = (int)((bm & 2047) >> 5) + cl;
    float Aa[NSTATE], Bb[NSTATE], h[NSTATE];
    #pragma unroll
    for (int n = 0; n < NSTATE; ++n) {
      Aa[n] = -__expf(A_log[d * NSTATE + n]);
      Bb[n] = Bp[d * NSTATE + n];
      h[n] = 0.f;
    }
    float sdt = 0.f;
    const long grow0 = bm + cl * 32;
    for (int i = 0; i < CLEN; ++i) {
      float dt = sX[(cl * 32 + i) * 128 + dl];
      float xv = bf2f(A[(grow0 + i) * (long)K + d]);   // A == xc_bf
      sdt += dt;
      float dx = dt * xv;
      #pragma unroll
      for (int n = 0; n < NSTATE; ++n) {
        float da = __expf(dt * Aa[n]);
        h[n] = fmaf(da, h[n], dx * Bb[n]);
      }
    }
    const long hb = ((long)(b * NCHUNK + cg) * NSTATE) * DI + d;
    #pragma unroll
    for (int n = 0; n < NSTATE; ++n) hfin[hb + (long)n * DI] = h[n];
    sumdt[(long)(b * NCHUNK + cg) * DI + d] = sdt;
  }
}

// ---------------- causal depthwise conv (K=4) + silu -> bf16, x8 vectorized ----
__global__ __launch_bounds__(256) void k_conv(
    const u16* __restrict__ xproj, const float* __restrict__ convw,
    const float* __restrict__ convb, u16* __restrict__ xcbf)
{
  const int idx = blockIdx.x * 256 + threadIdx.x;   // (m, d-octet)
  const int d0 = (idx & 127) * 8;
  const int m  = idx >> 7;
  const int l  = m & (SEQ - 1);
  float acc[8];
  #pragma unroll
  for (int di = 0; di < 8; ++di) acc[di] = convb[d0 + di];
  #pragma unroll
  for (int k = 0; k < 4; ++k) {
    if (l + k - 3 >= 0) {
      ushort4 v2 = *reinterpret_cast<const ushort4*>(&xproj[(long)(m + k - 3) * DI + d0]);
      ushort4 v3 = *reinterpret_cast<const ushort4*>(&xproj[(long)(m + k - 3) * DI + d0 + 4]);
      const u16 vv[8] = {v2.x, v2.y, v2.z, v2.w, v3.x, v3.y, v3.z, v3.w};
      #pragma unroll
      for (int di = 0; di < 8; ++di)
        acc[di] = fmaf(convw[(d0 + di) * 4 + k], bf2f(vv[di]), acc[di]);
    }
  }
  u16 ov[8];
  #pragma unroll
  for (int di = 0; di < 8; ++di) {
    float s = acc[di] * sigm(acc[di]);
    ov[di] = f2bf(s);
  }
  ushort4 o0 = {ov[0], ov[1], ov[2], ov[3]}, o1 = {ov[4], ov[5], ov[6], ov[7]};
  *reinterpret_cast<ushort4*>(&xcbf[(long)m * DI + d0]) = o0;
  *reinterpret_cast<ushort4*>(&xcbf[(long)m * DI + d0 + 4]) = o1;
}

// ---------------- scan combine + pass B ----------------
__global__ __launch_bounds__(256) void k_combine(
    const float* __restrict__ hfin, const float* __restrict__ sumdt_buf,
    const float* __restrict__ A_log, float* __restrict__ hstart)
{
  const int idx = blockIdx.x * 256 + threadIdx.x;   // 32768 threads
  const int d = idx & (DI - 1);
  const int n = (idx >> 10) & (NSTATE - 1);
  const int b = idx >> 14;
  const float Aa = -__expf(A_log[d * NSTATE + n]);
  float h = 0.f;
  for (int c = 0; c < NCHUNK; ++c) {
    const long sb = ((long)(b * NCHUNK + c) * NSTATE + n) * DI + d;
    hstart[sb] = h;
    float sdt = sumdt_buf[(long)(b * NCHUNK + c) * DI + d];
    h = fmaf(__expf(Aa * sdt), h, hfin[sb]);
  }
}

__global__ __launch_bounds__(256) void k_scanB(
    const u16* __restrict__ delta, const u16* __restrict__ xc,
    const float* __restrict__ A_log, const float* __restrict__ Bp,
    const float* __restrict__ Cp, const float* __restrict__ Dp,
    const u16* __restrict__ sres, const float* __restrict__ hstart,
    u16* __restrict__ gated)
{
  const int tid = threadIdx.x, blk = blockIdx.x;    // 512 blocks
  const int d = (blk & 3) * 256 + tid;
  const int c = (blk >> 2) & (NCHUNK - 1);
  const int b = blk >> 8;
  float Aa[NSTATE], Bb[NSTATE], Cc[NSTATE], h[NSTATE];
  #pragma unroll
  for (int n = 0; n < NSTATE; ++n) {
    Aa[n] = -__expf(A_log[d * NSTATE + n]);
    Bb[n] = Bp[d * NSTATE + n];
    Cc[n] = Cp[d * NSTATE + n];
  }
  const float Dd = Dp[d];
  const long sb = ((long)(b * NCHUNK + c) * NSTATE) * DI + d;
  #pragma unroll
  for (int n = 0; n < NSTATE; ++n) h[n] = hstart[sb + (long)n * DI];
  const long base = ((long)(b * SEQ + c * CLEN)) * DI + d;
  for (int i = 0; i < CLEN; ++i) {
    float dt = bf2f(delta[base + (long)i * DI]);
    float x  = bf2f(xc[base + (long)i * DI]);
    float dx = dt * x;
    float y = 0.f;
    #pragma unroll
    for (int n = 0; n < NSTATE; ++n) {
      float da = __expf(dt * Aa[n]);
      h[n] = fmaf(da, h[n], dx * Bb[n]);
      y = fmaf(h[n], Cc[n], y);
    }
    float xs = fmaf(x, Dd, y);
    float g = xs * bf2f(sres[base + (long)i * DI]);
    gated[base + (long)i * DI] = f2bf(g);
  }
}

// ---------------- host launch ----------------
extern "C" void kernel_launch(void* const* d_in, const int* in_sizes, int n_in,
                              void* d_out, int out_size, void* d_ws, size_t ws_size,
                              hipStream_t stream)
{
  const float* x      = (const float*)d_in[0];
  const float* W_in   = (const float*)d_in[1];
  const float* conv_w = (const float*)d_in[2];
  const float* conv_b = (const float*)d_in[3];
  const float* W_dt   = (const float*)d_in[4];
  const float* b_dt   = (const float*)d_in[5];
  const float* A_log  = (const float*)d_in[6];
  const float* Bp     = (const float*)d_in[7];
  const float* Cp     = (const float*)d_in[8];
  const float* Dp     = (const float*)d_in[9];
  const float* W_out  = (const float*)d_in[10];
  float* out = (float*)d_out;

  const long MD = (long)NROW * DI;          // 4194304

  char* ws = (char*)d_ws;
  u16*   xproj_bf = (u16*)ws;               ws += MD * 2;   // x_proj bf16
  u16*   silu_bf  = (u16*)ws;               ws += MD * 2;   // silu(res) bf16
  u16*   delta_bf = (u16*)ws;               ws += MD * 2;   // softplus out bf16
  u16*   xc_bf    = (u16*)ws;               ws += MD * 2;   // conv+silu bf16
  u16*   xbf      = (u16*)ws;               ws += MD * 2;   // x bf16; later gated
  u16*   Win_bf   = (u16*)ws;               ws += (long)2 * DI * DM * 2;
  u16*   Wdt_bf   = (u16*)ws;               ws += (long)DI * DI * 2;
  u16*   Wout_bf  = (u16*)ws;               ws += (long)DM * DI * 2;
  float* hfin     = (float*)ws;             ws += (long)BATCH * NCHUNK * NSTATE * DI * 4;
  float* sumdt    = (float*)ws;             ws += (long)BATCH * NCHUNK * DI * 4;
  float* hstart   = (float*)ws;             ws += (long)BATCH * NCHUNK * NSTATE * DI * 4;

  u16* gated = xbf;      // alias: x_bf16 dead before gated is written

  // 1) fused fp32 -> bf16 conversion (x, W_in, W_dt, W_out)
  k_cvt_all<<<dim3(8192), dim3(256), 0, stream>>>(
      x, W_in, W_dt, W_out, xbf, Win_bf, Wdt_bf, Wout_bf);

  // 2) GEMM1: xr = x @ W_in^T -> x_proj (bf16), silu_res (bf16); grid 512
  k_gemm1<<<dim3(512), dim3(256), 0, stream>>>(
      xbf, Win_bf, xproj_bf, silu_bf, NROW, 2 * DI, DM);

  // 3) causal depthwise conv + silu -> bf16 (x8 vectorized)
  k_conv<<<dim3((unsigned)(MD / 8 / 256)), dim3(256), 0, stream>>>(
      xproj_bf, conv_w, conv_b, xc_bf);

  // 4) GEMM2 split-K-in-block + fused softplus + scanA; grid 256 x 512thr
  k_gemm_skb<3><<<dim3(256), dim3(512), 0, stream>>>(
      xc_bf, Wdt_bf, nullptr, delta_bf, b_dt,
      A_log, Bp, hfin, sumdt, NROW, DI, DI);

  // 5) combine + scanB
  k_combine<<<dim3(BATCH * NSTATE * DI / 256), dim3(256), 0, stream>>>(
      hfin, sumdt, A_log, hstart);
  k_scanB<<<dim3(BATCH * NCHUNK * (DI / 256)), dim3(256), 0, stream>>>(
      delta_bf, xc_bf, A_log, Bp, Cp, Dp, silu_bf, hstart, gated);

  // 6) GEMM3 split-K-in-block -> fp32 out; grid 256 x 512thr
  k_gemm_skb<0><<<dim3(256), dim3(512), 0, stream>>>(
      gated, Wout_bf, out, nullptr, nullptr,
      nullptr, nullptr, nullptr, nullptr, NROW, DM, DI);
}